// Round 6
// baseline (130.767 us; speedup 1.0000x reference)
//
#include <hip/hip_runtime.h>

// FreqLinear: out = Y2 @ float(idx)^T + corr[m] + bias[o], K = 2048.
// GEMM v6: PRODUCER/CONSUMER WAVE SPECIALIZATION + B-resident LDS.
// grid 256 x 512thr. Block = 32 cols x 256 rows; B operand (32x2048 bf16 =
// 128 KB) resident in LDS, each 256-K chunk region written exactly once.
//   waves 4..7 (producers): free-run idx HBM stream (depth-2 chunk regs ->
//     cvt bf16 -> XOR-swizzled LDS -> publish flags[c] via LDS atomic).
//     Never wait on consumers.
//   waves 0..3 (consumers): 64 rows each; spin on flags[c]==4, then 8 ksteps
//     x (4 mg x 2 g) MFMA; A-frags via depth-4 register ring from global
//     (L2-hot). Consumer vmcnt queue holds ONLY A-loads -> fully decoupled
//     from the HBM stream. One s_barrier total (flag init).

typedef __attribute__((ext_vector_type(8))) short bf16x8;   // 8 bf16
typedef __attribute__((ext_vector_type(4))) float f32x4;

#define K_TOT   2048
#define N_TOT   8192
#define NT      32        // cols per block
#define NCHUNK  8         // K chunks of 256
#define SPC     8         // ksteps (K=32) per chunk
#define LDS_CH  16384     // bytes per chunk region: 32 cols * 256 * 2B

__device__ __forceinline__ unsigned short f2bf_rn(float f) {
    unsigned u = __float_as_uint(f);
    u += 0x7FFFu + ((u >> 16) & 1u);
    return (unsigned short)(u >> 16);
}
// two ints (0..255) -> exact floats -> packed bf16 pair (truncation exact)
__device__ __forceinline__ unsigned pack2(int a, int b) {
    unsigned ua = __float_as_uint((float)a);
    unsigned ub = __float_as_uint((float)b);
    return __builtin_amdgcn_perm(ub, ua, 0x07060302u);
}

__device__ __forceinline__ void lds_barrier() {
    asm volatile("" ::: "memory");
    __builtin_amdgcn_s_waitcnt(0xC07F);   // lgkmcnt(0) only
    __builtin_amdgcn_s_barrier();
    asm volatile("" ::: "memory");
}

// ---------------- Kernel A: build Y2f (bf16, frag order) + corr ------------
__global__ __launch_bounds__(256) void prep_kernel(
    const float* __restrict__ x, const float* __restrict__ c_min,
    const float* __restrict__ c_range, unsigned short* __restrict__ Y2f,
    float* __restrict__ corr)
{
    __shared__ float Bk[8][16];
    __shared__ float scmin[8];
    __shared__ float ss[8];
    __shared__ float red[4];
    const int tid = threadIdx.x;
    const int m = blockIdx.x;
    if (tid < 128) {
        int k = tid >> 4, t = tid & 15;
        float v = cosf(3.14159265358979f * (t + 0.5f) * (float)k / 16.0f)
                  * 0.353553390593274f;                 // sqrt(2/16)
        if (k == 0) v *= 0.707106781186548f;            // 1/sqrt(2)
        Bk[k][t] = v;
    }
    if (tid < 8) {
        scmin[tid] = c_min[tid];
        ss[tid] = c_range[tid] * (1.0f / 255.0f);
    }
    __syncthreads();

    const float* xp = x + (long)m * 4096 + tid * 16;
    float xs[16];
#pragma unroll
    for (int q = 0; q < 4; ++q) {
        float4 v = *(const float4*)(xp + q * 4);
        xs[q * 4 + 0] = v.x; xs[q * 4 + 1] = v.y;
        xs[q * 4 + 2] = v.z; xs[q * 4 + 3] = v.w;
    }
    float partial = 0.0f;
    unsigned short yo[8];
#pragma unroll
    for (int k = 0; k < 8; ++k) {
        float y = 0.0f;
#pragma unroll
        for (int t = 0; t < 16; ++t) y += xs[t] * Bk[k][t];
        partial += y * scmin[k];
        yo[k] = f2bf_rn(y * ss[k]);
    }
    uint4 pk;
    pk.x = (unsigned)yo[0] | ((unsigned)yo[1] << 16);
    pk.y = (unsigned)yo[2] | ((unsigned)yo[3] << 16);
    pk.z = (unsigned)yo[4] | ((unsigned)yo[5] << 16);
    pk.w = (unsigned)yo[6] | ((unsigned)yo[7] << 16);
    // frag-order store: kc = tid>>2, fq = tid&3, mg = m>>4, fr = m&15
    {
        const int mg = m >> 4, fr = m & 15, kc = tid >> 2, fq = tid & 3;
        unsigned short* dst = Y2f + ((long)((mg * 64 + kc) * 64) + fq * 16 + fr) * 8;
        *(uint4*)dst = pk;
    }
#pragma unroll
    for (int off = 32; off > 0; off >>= 1)
        partial += __shfl_down(partial, off, 64);
    if ((tid & 63) == 0) red[tid >> 6] = partial;
    __syncthreads();
    if (tid == 0) corr[m] = red[0] + red[1] + red[2] + red[3];
}

// ---------------- Kernel B ------------------------------------------------
__global__ __launch_bounds__(512, 2) void gemm_kernel(
    const unsigned short* __restrict__ Y2f, const int* __restrict__ idx,
    const float* __restrict__ bias, const float* __restrict__ corr,
    float* __restrict__ out)
{
    __shared__ char lds[NCHUNK * LDS_CH];     // 128 KB, B-resident
    __shared__ int flags[NCHUNK];

    const int tid  = threadIdx.x;
    const int wave = tid >> 6;
    const int lane = tid & 63;
    const int o0   = blockIdx.x * NT;

    if (tid < NCHUNK) flags[tid] = 0;

    if (wave >= 4) {
        // ================= PRODUCER (waves 4..7, 256 threads) ==============
        const int p    = tid - 256;     // 0..255
        const int scol = p >> 3;        // 0..31
        const int sk8  = p & 7;         // int4-slot within col: kq = sk8 + r*8
        const int* pBase = idx + (long)(o0 + scol) * K_TOT + sk8 * 4;

        int4 S[2][8];
#define PLOAD(slot, ch)                                                   \
        {                                                                 \
            _Pragma("unroll")                                             \
            for (int r = 0; r < 8; ++r)                                   \
                S[slot][r] = *(const int4*)(pBase + (ch) * 256 + r * 32); \
        }
        PLOAD(0, 0)
        PLOAD(1, 1)
        lds_barrier();      // flags visible; LDS regions free to write

#pragma unroll
        for (int c = 0; c < NCHUNK; ++c) {
            char* buf = lds + c * LDS_CH;
#pragma unroll
            for (int r = 0; r < 8; ++r) {
                const int kq = sk8 + r * 8;
                uint2 w;
                w.x = pack2(S[c & 1][r].x, S[c & 1][r].y);
                w.y = pack2(S[c & 1][r].z, S[c & 1][r].w);
                *(uint2*)(buf + scol * 512 + (((kq >> 1) ^ scol) * 16)
                          + (kq & 1) * 8) = w;
            }
            __builtin_amdgcn_s_waitcnt(0xC07F);   // ds_writes drained
            if (lane == 0)
                __hip_atomic_fetch_add(&flags[c], 1, __ATOMIC_RELEASE,
                                       __HIP_MEMORY_SCOPE_WORKGROUP);
            // refill slot with chunk c+2 (clamped; tail refill is redundant
            // but keeps the loop branch-free and in-bounds)
            const int nc = (c + 2 < NCHUNK) ? (c + 2) : (NCHUNK - 1);
            PLOAD(c & 1, nc)
        }
#undef PLOAD
    } else {
        // ================= CONSUMER (waves 0..3) ===========================
        const int fr = lane & 15;
        const int fq = lane >> 4;
        // A frags: mg = wave*4 + mt; frag(mg,ks) at bf16x8 idx (mg*64+ks)*64+lane
        const bf16x8* aF = (const bf16x8*)Y2f + (long)(wave * 4) * 64 * 64 + lane;
        // mt stride = 64*64 = 4096 frags; ks stride = 64 frags

        f32x4 acc[4][2];
#pragma unroll
        for (int mt = 0; mt < 4; ++mt)
#pragma unroll
            for (int g = 0; g < 2; ++g)
                acc[mt][g] = (f32x4){0.f, 0.f, 0.f, 0.f};

        bf16x8 a[4][4];    // depth-4 kstep ring x 4 mg
#pragma unroll
        for (int d = 0; d < 4; ++d)
#pragma unroll
            for (int mt = 0; mt < 4; ++mt)
                a[d][mt] = aF[mt * 4096 + d * 64];

        lds_barrier();

#define BREAD(buf, s, g)                                                  \
    (*(const bf16x8*)((buf) + (g * 16 + fr) * 512 +                       \
                      ((((s) * 4 + fq) ^ (g * 16 + fr)) * 16)))

        for (int c = 0; c < NCHUNK; ++c) {
            while (__hip_atomic_load(&flags[c], __ATOMIC_ACQUIRE,
                                     __HIP_MEMORY_SCOPE_WORKGROUP) < 4)
                __builtin_amdgcn_s_sleep(1);
            const char* buf = lds + c * LDS_CH;
#pragma unroll
            for (int s = 0; s < SPC; ++s) {
                bf16x8 b0 = BREAD(buf, s, 0);
                bf16x8 b1 = BREAD(buf, s, 1);
#pragma unroll
                for (int mt = 0; mt < 4; ++mt) {
                    acc[mt][0] = __builtin_amdgcn_mfma_f32_16x16x32_bf16(
                        a[s & 3][mt], b0, acc[mt][0], 0, 0, 0);
                    acc[mt][1] = __builtin_amdgcn_mfma_f32_16x16x32_bf16(
                        a[s & 3][mt], b1, acc[mt][1], 0, 0, 0);
                }
                // refill ring slot with kstep c*8+s+4 (runs past K on the
                // tail: reads land in d_ws scratch beyond Y2f -- unused)
                {
                    const long nks = (long)c * SPC + s + 4;
#pragma unroll
                    for (int mt = 0; mt < 4; ++mt)
                        a[s & 3][mt] = aF[mt * 4096 + nks * 64];
                }
            }
        }
#undef BREAD

        // epilogue: D layout col=lane&15, row=(lane>>4)*4+reg
#pragma unroll
        for (int mt = 0; mt < 4; ++mt) {
#pragma unroll
            for (int g = 0; g < 2; ++g) {
                const int col = o0 + g * 16 + fr;
                const float bv = bias[col];
                const int row0 = (wave * 4 + mt) * 16 + fq * 4;
#pragma unroll
                for (int r = 0; r < 4; ++r)
                    out[(long)(row0 + r) * N_TOT + col] =
                        acc[mt][g][r] + bv + corr[row0 + r];
            }
        }
    }
}

extern "C" void kernel_launch(void* const* d_in, const int* in_sizes, int n_in,
                              void* d_out, int out_size, void* d_ws, size_t ws_size,
                              hipStream_t stream) {
    const float* x       = (const float*)d_in[0];   // [32,8,4096]
    const int*   idx     = (const int*)d_in[1];     // [2097152, 8]
    const float* c_min   = (const float*)d_in[2];   // [8]
    const float* c_range = (const float*)d_in[3];   // [8]
    const float* bias    = (const float*)d_in[4];   // [8192]
    float* out = (float*)d_out;                     // [256, 8192]

    unsigned short* Y2f = (unsigned short*)d_ws;                   // 1 MB
    float* corr = (float*)((char*)d_ws + (size_t)256 * K_TOT * 2); // 256 fp32

    prep_kernel<<<256, 256, 0, stream>>>(x, c_min, c_range, Y2f, corr);
    gemm_kernel<<<256, 512, 0, stream>>>(Y2f, idx, bias, corr, out);
}

// Round 7
// 120.578 us; speedup vs baseline: 1.0845x; 1.0845x over previous
//
#include <hip/hip_runtime.h>

// FreqLinear: out = Y2 @ float(idx)^T + corr[m] + bias[o], K = 2048.
// GEMM v7: producer/consumer waves + B-resident LDS + RAW LDS signaling.
// v6's __hip_atomic RELEASE/ACQUIRE made LLVM emit s_waitcnt vmcnt(0) around
// every flag op -- draining the HBM stream (producers) and the A-ring
// (consumers) once per chunk. v7 signals with plain volatile LDS stores
// guarded by an inline-asm `s_waitcnt lgkmcnt(0)` (LDS-only, vmcnt untouched).
//   waves 4..7 (producers): free-run idx stream, depth-2 chunk reg ring,
//     cvt bf16, conflict-free swizzled ds_write_b128, per-wave flag slot.
//   waves 0..3 (consumers): poll 4 flag slots (volatile), 8 ksteps x
//     (4 mg x 2 g) MFMA; A-frags via depth-8 register ring (L2-hot) --
//     consumer vmcnt queue holds ONLY A-loads.
// LDS map per chunk: addr(col,pair) = col*512 + ((pair^col)*16), pair=0..31
// (16B k-units). Writes: lane covers (col = pw*8+(l>>3), pair=(l&7)+8r) ->
// 8 lanes per 4-bank group per instr = conflict-free. Reads (s,fq,col):
// pair = s*4+fq -> also 8 lanes/group = conflict-free.

typedef __attribute__((ext_vector_type(8))) short bf16x8;   // 8 bf16
typedef __attribute__((ext_vector_type(4))) float f32x4;

#define K_TOT   2048
#define N_TOT   8192
#define NT      32        // cols per block
#define NCHUNK  8         // K chunks of 256
#define SPC     8         // ksteps (K=32) per chunk
#define LDS_CH  16384     // bytes per chunk region: 32 cols * 256 * 2B

__device__ __forceinline__ unsigned short f2bf_rn(float f) {
    unsigned u = __float_as_uint(f);
    u += 0x7FFFu + ((u >> 16) & 1u);
    return (unsigned short)(u >> 16);
}
// two ints (0..255) -> exact floats -> packed bf16 pair (truncation exact)
__device__ __forceinline__ unsigned pack2(int a, int b) {
    unsigned ua = __float_as_uint((float)a);
    unsigned ub = __float_as_uint((float)b);
    return __builtin_amdgcn_perm(ub, ua, 0x07060302u);
}

__device__ __forceinline__ void lds_barrier() {
    asm volatile("" ::: "memory");
    __builtin_amdgcn_s_waitcnt(0xC07F);   // lgkmcnt(0) only
    __builtin_amdgcn_s_barrier();
    asm volatile("" ::: "memory");
}

// ---------------- Kernel A: build Y2f (bf16, frag order) + corr ------------
__global__ __launch_bounds__(256) void prep_kernel(
    const float* __restrict__ x, const float* __restrict__ c_min,
    const float* __restrict__ c_range, unsigned short* __restrict__ Y2f,
    float* __restrict__ corr)
{
    __shared__ float Bk[8][16];
    __shared__ float scmin[8];
    __shared__ float ss[8];
    __shared__ float red[4];
    const int tid = threadIdx.x;
    const int m = blockIdx.x;
    if (tid < 128) {
        int k = tid >> 4, t = tid & 15;
        float v = cosf(3.14159265358979f * (t + 0.5f) * (float)k / 16.0f)
                  * 0.353553390593274f;                 // sqrt(2/16)
        if (k == 0) v *= 0.707106781186548f;            // 1/sqrt(2)
        Bk[k][t] = v;
    }
    if (tid < 8) {
        scmin[tid] = c_min[tid];
        ss[tid] = c_range[tid] * (1.0f / 255.0f);
    }
    __syncthreads();

    const float* xp = x + (long)m * 4096 + tid * 16;
    float xs[16];
#pragma unroll
    for (int q = 0; q < 4; ++q) {
        float4 v = *(const float4*)(xp + q * 4);
        xs[q * 4 + 0] = v.x; xs[q * 4 + 1] = v.y;
        xs[q * 4 + 2] = v.z; xs[q * 4 + 3] = v.w;
    }
    float partial = 0.0f;
    unsigned short yo[8];
#pragma unroll
    for (int k = 0; k < 8; ++k) {
        float y = 0.0f;
#pragma unroll
        for (int t = 0; t < 16; ++t) y += xs[t] * Bk[k][t];
        partial += y * scmin[k];
        yo[k] = f2bf_rn(y * ss[k]);
    }
    uint4 pk;
    pk.x = (unsigned)yo[0] | ((unsigned)yo[1] << 16);
    pk.y = (unsigned)yo[2] | ((unsigned)yo[3] << 16);
    pk.z = (unsigned)yo[4] | ((unsigned)yo[5] << 16);
    pk.w = (unsigned)yo[6] | ((unsigned)yo[7] << 16);
    // frag-order store: kc = tid>>2, fq = tid&3, mg = m>>4, fr = m&15
    {
        const int mg = m >> 4, fr = m & 15, kc = tid >> 2, fq = tid & 3;
        unsigned short* dst = Y2f + ((long)((mg * 64 + kc) * 64) + fq * 16 + fr) * 8;
        *(uint4*)dst = pk;
    }
#pragma unroll
    for (int off = 32; off > 0; off >>= 1)
        partial += __shfl_down(partial, off, 64);
    if ((tid & 63) == 0) red[tid >> 6] = partial;
    __syncthreads();
    if (tid == 0) corr[m] = red[0] + red[1] + red[2] + red[3];
}

// ---------------- Kernel B ------------------------------------------------
__global__ __launch_bounds__(512, 2) void gemm_kernel(
    const unsigned short* __restrict__ Y2f, const int* __restrict__ idx,
    const float* __restrict__ bias, const float* __restrict__ corr,
    float* __restrict__ out)
{
    __shared__ char lds[NCHUNK * LDS_CH];     // 128 KB, B-resident
    __shared__ int flags[NCHUNK][4];

    const int tid  = threadIdx.x;
    const int wave = tid >> 6;
    const int lane = tid & 63;
    const int o0   = blockIdx.x * NT;

    if (tid < NCHUNK * 4) flags[tid >> 2][tid & 3] = 0;

    if (wave >= 4) {
        // ================= PRODUCER (waves 4..7) ===========================
        const int pw   = wave - 4;                 // 0..3
        const int col  = pw * 8 + (lane >> 3);     // 0..31
        const int pr0  = lane & 7;                 // pair = pr0 + 8r
        const int* pBase = idx + (long)(o0 + col) * K_TOT + pr0 * 8;
        char* cBase = lds + col * 512;

        int4 S[2][4][2];   // 2 chunks x 4 units x 2 int4
#define PLOAD(slot, ch)                                                   \
        {                                                                 \
            _Pragma("unroll")                                             \
            for (int r = 0; r < 4; ++r) {                                 \
                const int* p = pBase + (ch) * 256 + r * 64;               \
                S[slot][r][0] = *(const int4*)p;                          \
                S[slot][r][1] = *(const int4*)(p + 4);                    \
            }                                                             \
        }
        PLOAD(0, 0)
        PLOAD(1, 1)
        lds_barrier();      // flags init visible

#pragma unroll
        for (int c = 0; c < NCHUNK; ++c) {
#pragma unroll
            for (int r = 0; r < 4; ++r) {
                uint4 w;
                w.x = pack2(S[c & 1][r][0].x, S[c & 1][r][0].y);
                w.y = pack2(S[c & 1][r][0].z, S[c & 1][r][0].w);
                w.z = pack2(S[c & 1][r][1].x, S[c & 1][r][1].y);
                w.w = pack2(S[c & 1][r][1].z, S[c & 1][r][1].w);
                *(uint4*)(cBase + c * LDS_CH + (((pr0 + 8 * r) ^ col) * 16)) = w;
            }
            // LDS-only drain; the idx HBM stream (vmcnt) stays in flight
            asm volatile("s_waitcnt lgkmcnt(0)" ::: "memory");
            if (lane == 0) *(volatile int*)&flags[c][pw] = 1;
            const int nc = (c + 2 < NCHUNK) ? (c + 2) : (NCHUNK - 1);
            PLOAD(c & 1, nc)
        }
#undef PLOAD
    } else {
        // ================= CONSUMER (waves 0..3) ===========================
        const int fr = lane & 15;
        const int fq = lane >> 4;
        // A frags: mg = wave*4 + mt; frag(mg,ks) at bf16x8 idx mg*4096+ks*64+lane
        const bf16x8* aF = (const bf16x8*)Y2f + (long)(wave * 4) * 4096 + lane;

        f32x4 acc[4][2];
#pragma unroll
        for (int mt = 0; mt < 4; ++mt)
#pragma unroll
            for (int g = 0; g < 2; ++g)
                acc[mt][g] = (f32x4){0.f, 0.f, 0.f, 0.f};

        bf16x8 a[8][4];    // depth-8 kstep ring x 4 mg
#pragma unroll
        for (int d = 0; d < 8; ++d)
#pragma unroll
            for (int mt = 0; mt < 4; ++mt)
                a[d][mt] = aF[mt * 4096 + d * 64];

        lds_barrier();

#define BREAD(buf, s, g)                                                  \
    (*(const bf16x8*)((buf) + (g * 16 + fr) * 512 +                       \
                      ((((s) * 4 + fq) ^ (g * 16 + fr)) * 16)))

#pragma unroll
        for (int c = 0; c < NCHUNK; ++c) {
            // raw volatile poll -- no vmcnt drain
            for (;;) {
                int f0 = *(volatile int*)&flags[c][0];
                int f1 = *(volatile int*)&flags[c][1];
                int f2 = *(volatile int*)&flags[c][2];
                int f3 = *(volatile int*)&flags[c][3];
                if (f0 & f1 & f2 & f3) break;
            }
            asm volatile("" ::: "memory");
            const char* buf = lds + c * LDS_CH;
#pragma unroll
            for (int s = 0; s < SPC; ++s) {
                bf16x8 b0 = BREAD(buf, s, 0);
                bf16x8 b1 = BREAD(buf, s, 1);
#pragma unroll
                for (int mt = 0; mt < 4; ++mt) {
                    acc[mt][0] = __builtin_amdgcn_mfma_f32_16x16x32_bf16(
                        a[s][mt], b0, acc[mt][0], 0, 0, 0);
                    acc[mt][1] = __builtin_amdgcn_mfma_f32_16x16x32_bf16(
                        a[s][mt], b1, acc[mt][1], 0, 0, 0);
                }
                // refill ring slot with kstep (c*8+s+8) mod 64 (tail wraps:
                // harmlessly reloads head, values unused)
                {
                    const int nks = (c * SPC + s + 8) & 63;
#pragma unroll
                    for (int mt = 0; mt < 4; ++mt)
                        a[s][mt] = aF[mt * 4096 + nks * 64];
                }
            }
        }
#undef BREAD

        // epilogue: D layout col=lane&15, row=(lane>>4)*4+reg
#pragma unroll
        for (int mt = 0; mt < 4; ++mt) {
#pragma unroll
            for (int g = 0; g < 2; ++g) {
                const int col = o0 + g * 16 + fr;
                const float bv = bias[col];
                const int row0 = (wave * 4 + mt) * 16 + fq * 4;
#pragma unroll
                for (int r = 0; r < 4; ++r)
                    out[(long)(row0 + r) * N_TOT + col] =
                        acc[mt][g][r] + bv + corr[row0 + r];
            }
        }
    }
}

extern "C" void kernel_launch(void* const* d_in, const int* in_sizes, int n_in,
                              void* d_out, int out_size, void* d_ws, size_t ws_size,
                              hipStream_t stream) {
    const float* x       = (const float*)d_in[0];   // [32,8,4096]
    const int*   idx     = (const int*)d_in[1];     // [2097152, 8]
    const float* c_min   = (const float*)d_in[2];   // [8]
    const float* c_range = (const float*)d_in[3];   // [8]
    const float* bias    = (const float*)d_in[4];   // [8192]
    float* out = (float*)d_out;                     // [256, 8192]

    unsigned short* Y2f = (unsigned short*)d_ws;                   // 1 MB
    float* corr = (float*)((char*)d_ws + (size_t)256 * K_TOT * 2); // 256 fp32

    prep_kernel<<<256, 256, 0, stream>>>(x, c_min, c_range, Y2f, corr);
    gemm_kernel<<<256, 512, 0, stream>>>(Y2f, idx, bias, corr, out);
}